// Round 4
// baseline (136.285 us; speedup 1.0000x reference)
//
#include <hip/hip_runtime.h>
#include <stdint.h>

#define NT 2048     // tokens
#define TD 1024     // token dim
#define NH 16       // heads
static constexpr float SCL = 0.18033688011112042f;  // beta*log2(e), folded into K cols

typedef __attribute__((ext_vector_type(8))) short bf16x8;
typedef __attribute__((ext_vector_type(4))) float f32x4;
typedef __attribute__((address_space(3))) uint32_t lds_u32;
typedef __attribute__((address_space(1))) uint32_t glb_u32;

__device__ __forceinline__ float bf2f(unsigned short u){
  union { uint32_t u32; float f; } v; v.u32 = ((uint32_t)u) << 16; return v.f;
}
__device__ __forceinline__ unsigned short f2bf(float f){
  union { float f; uint32_t u; } v; v.f = f;
  uint32_t r = v.u + 0x7fffu + ((v.u >> 16) & 1u);   // RNE
  return (unsigned short)(r >> 16);
}
// swizzled LDS fragment read: tiles are [rows][64 bf16 = 128 B], slot = 16B unit,
// physical slot = logical ^ (row&7). Returns 8 bf16 at logical 16B slot (k2*4+g).
__device__ __forceinline__ bf16x8 ldswz(const unsigned short* base, int row, int k2, int g){
  return *(const bf16x8*)((const char*)base + row*128 + ((((k2<<2)+g)^(row&7))<<4));
}
template<int N> __device__ __forceinline__ void wait_vm_lgkm0(){
  if constexpr (N == 0)      asm volatile("s_waitcnt vmcnt(0) lgkmcnt(0)" ::: "memory");
  else if constexpr (N == 4) asm volatile("s_waitcnt vmcnt(4) lgkmcnt(0)" ::: "memory");
  else if constexpr (N == 6) asm volatile("s_waitcnt vmcnt(6) lgkmcnt(0)" ::: "memory");
  __builtin_amdgcn_sched_barrier(0);
}

// ------------------------------------------------------------------
// prep: gbf = bf16(g); wkq = bf16([Wk;Wq]) rows hz2 x 1024;
//       twqk[d][j] = j<1024 ? Wq[j][d] : Wk[j-1024][d]  (bf16, 1024x2048)
// ------------------------------------------------------------------
__global__ __launch_bounds__(256) void prep_kernel(
    const float* __restrict__ g, const float* __restrict__ Wk, const float* __restrict__ Wq,
    unsigned short* __restrict__ gbf, unsigned short* __restrict__ wkq,
    unsigned short* __restrict__ twqk)
{
  int b = blockIdx.x;
  if (b < 1024) {
    int base = b * 2048 + threadIdx.x;
    #pragma unroll
    for (int i = 0; i < 8; i++) { int idx = base + i * 256; gbf[idx] = f2bf(g[idx]); }
  } else if (b < 2048) {
    int base = (b - 1024) * 2048 + threadIdx.x;
    #pragma unroll
    for (int i = 0; i < 8; i++) {
      int idx = base + i * 256;
      float v = (idx < (1 << 20)) ? Wk[idx] : Wq[idx - (1 << 20)];
      wkq[idx] = f2bf(v);
    }
  } else {
    int t = b - 2048;                  // 32 d-tiles x 64 j-tiles
    int dt = t & 31, jt = t >> 5;
    __shared__ float tile[32][33];
    int tx = threadIdx.x & 31, ty = threadIdx.x >> 5;
    int j0 = jt * 32, d0 = dt * 32;
    const float* src = (j0 < 1024) ? Wq : Wk;
    int jb = (j0 < 1024) ? j0 : (j0 - 1024);
    #pragma unroll
    for (int rr = 0; rr < 4; rr++)
      tile[ty + rr * 8][tx] = src[(size_t)(jb + ty + rr * 8) * 1024 + d0 + tx];
    __syncthreads();
    #pragma unroll
    for (int rr = 0; rr < 4; rr++)
      twqk[(size_t)(d0 + ty + rr * 8) * 2048 + j0 + tx] = f2bf(tile[tx][ty + rr * 8]);
  }
}

// ------------------------------------------------------------------
// qst: QsT[r][q] = TKQ[1024+r][q] / L[r>>6][q]
// ------------------------------------------------------------------
__global__ __launch_bounds__(256) void qst_kernel(const unsigned short* __restrict__ tkq,
                                                  const float* __restrict__ L,
                                                  unsigned short* __restrict__ qst)
{
  int r = blockIdx.x;
  int h = r >> 6;
  const unsigned short* src = tkq + (size_t)(1024 + r) * 2048;
  unsigned short* dst = qst + (size_t)r * 2048;
  const float* Lh = L + (size_t)h * NT;
  for (int q = threadIdx.x; q < NT; q += 256)
    dst[q] = f2bf(bf2f(src[q]) / Lh[q]);
}

// ------------------------------------------------------------------
// btg2: C = A[M x K] * BT[N x K]^T, bf16, BK=64, TRIPLE-buffered with
// counted vmcnt (T3/T4: prefetch depth 2, never drain to 0 mid-loop).
// Swizzled LDS (row&7 XOR on 16B slots, matched pre-swizzled global source).
// EPI 0: C0 = bf16 C (ld 2048), K-cols (bn<1024) pre-scaled by SCL;
//        C1 = transposed bf16 (ld 2048), UNSCALED                    [KQ]
// EPI 4: C0 f32 [r][1024] = -acc                                     [out]
// ------------------------------------------------------------------
template<int TM, int TN, int EPI>
__global__ __launch_bounds__(256, 2) void btg2_kernel(
    const unsigned short* __restrict__ A, int lda,
    const unsigned short* __restrict__ BT, int ldb,
    int Kdim, void* C0, void* C1)
{
  constexpr int WM = TM / 2, WN = TN / 2, FM = WM / 16, FN = WN / 16;
  constexpr int AC = TM / 32, BC = TN / 32, LOADS = AC + BC;
  __shared__ __align__(16) unsigned short As[3][TM * 64];
  __shared__ __align__(16) unsigned short Bs[3][TN * 64];
  int tid = threadIdx.x, lane = tid & 63, wave = tid >> 6;
  int wr = wave >> 1, wc = wave & 1, lrow = lane & 15, g = lane >> 4;
  int bm = blockIdx.x * TM, bn = blockIdx.y * TN;

  auto stage = [&](unsigned short* bufA, unsigned short* bufB, int kk) {
    #pragma unroll
    for (int i = 0; i < AC; i++) {
      int c = i * 256 + tid, row = c >> 3, sl = ((c & 7) ^ (row & 7)) << 3;
      __builtin_amdgcn_global_load_lds((glb_u32*)(A + (size_t)(bm + row) * lda + kk + sl),
          (lds_u32*)((char*)bufA + i * 4096 + wave * 1024), 16, 0, 0);
    }
    #pragma unroll
    for (int i = 0; i < BC; i++) {
      int c = i * 256 + tid, row = c >> 3, sl = ((c & 7) ^ (row & 7)) << 3;
      __builtin_amdgcn_global_load_lds((glb_u32*)(BT + (size_t)(bn + row) * ldb + kk + sl),
          (lds_u32*)((char*)bufB + i * 4096 + wave * 1024), 16, 0, 0);
    }
  };

  f32x4 acc[FM][FN] = {};
  int nt = Kdim >> 6;
  stage(As[0], Bs[0], 0);
  stage(As[1], Bs[1], 64);
  wait_vm_lgkm0<LOADS>();          // tile0 landed; tile1 still in flight
  __builtin_amdgcn_s_barrier();
  int bc = 0;
  for (int t = 0; t < nt; t++) {
    int bp = bc + 2; if (bp >= 3) bp -= 3;
    if (t + 2 < nt) stage(As[bp], Bs[bp], (t + 2) * 64);
    const unsigned short* Ac = As[bc];
    const unsigned short* Bc = Bs[bc];
    #pragma unroll
    for (int k2 = 0; k2 < 2; k2++) {
      bf16x8 a_[FM], b_[FN];
      #pragma unroll
      for (int m = 0; m < FM; m++) a_[m] = ldswz(Ac, wr * WM + m * 16 + lrow, k2, g);
      #pragma unroll
      for (int n = 0; n < FN; n++) b_[n] = ldswz(Bc, wc * WN + n * 16 + lrow, k2, g);
      #pragma unroll
      for (int m = 0; m < FM; m++)
        #pragma unroll
        for (int n = 0; n < FN; n++)
          acc[m][n] = __builtin_amdgcn_mfma_f32_16x16x32_bf16(a_[m], b_[n], acc[m][n], 0, 0, 0);
    }
    if (t + 2 < nt) wait_vm_lgkm0<LOADS>(); else wait_vm_lgkm0<0>();
    __builtin_amdgcn_s_barrier();
    bc = (bc == 2) ? 0 : bc + 1;
  }
  #pragma unroll
  for (int m = 0; m < FM; m++) {
    int rb = bm + wr * WM + m * 16 + 4 * g;
    #pragma unroll
    for (int n = 0; n < FN; n++) {
      int cc = bn + wc * WN + n * 16 + lrow;
      f32x4 v = acc[m][n];
      if constexpr (EPI == 0) {
        unsigned short* Cp = (unsigned short*)C0;
        unsigned short* T  = (unsigned short*)C1;
        float sc = (bn < 1024) ? SCL : 1.0f;   // pre-scale K features for exp2 path
        unsigned short pt[4];
        #pragma unroll
        for (int j = 0; j < 4; j++) {
          pt[j] = f2bf(v[j]);
          Cp[(size_t)(rb + j) * 2048 + cc] = f2bf(v[j] * sc);
        }
        ushort4 t4; t4.x = pt[0]; t4.y = pt[1]; t4.z = pt[2]; t4.w = pt[3];
        *(ushort4*)(T + (size_t)cc * 2048 + rb) = t4;
      } else {
        float* Cf = (float*)C0;
        #pragma unroll
        for (int j = 0; j < 4; j++) Cf[(size_t)(rb + j) * 1024 + cc] = -v[j];
      }
    }
  }
}

// ------------------------------------------------------------------
// fused flash kernel (F1: DIV computes B1 + L; F2: B2). Round-2-verified
// layout (P via Plds), plus: triple-buffer counted-vmcnt staging, hoisted
// Pblk fragments, exp2 (K pre-scaled), cvt_pk pack, L via ones-MFMA, setprio.
// ------------------------------------------------------------------
template<bool DIV>
__global__ __launch_bounds__(256, 2) void fused_kernel(
    const unsigned short* __restrict__ CKQ,   // [2048][2048]: K*SCL cols 0:1024, Q cols 1024:2048
    const unsigned short* __restrict__ AUXT,  // TKQ (F1, unscaled K^T) or QsT (F2): rows h*64+z
    unsigned short* __restrict__ C,           // CB12 [2048][2048]
    float* __restrict__ Lg)                   // [16][2048] (F1 only)
{
  __shared__ __align__(16) unsigned short Pblk[64 * 64];
  __shared__ __align__(16) unsigned short Ain[3][64 * 64];
  __shared__ __align__(16) unsigned short Auxs[3][64 * 64];
  __shared__ __align__(16) unsigned short Plds[64 * 64];
  __shared__ float L_lds[64];
  int tid = threadIdx.x, lane = tid & 63, wave = tid >> 6;
  int wr = wave >> 1, wc = wave & 1, lrow = lane & 15, g = lane >> 4;
  int p0 = blockIdx.x * 64, h = blockIdx.y, h64 = h * 64;
  int cA = DIV ? h64 : TD + h64;            // inner-tile cols (F1: K*SCL, F2: Q)
  int cB = DIV ? TD + h64 : h64;            // persistent cols (F1: Q, F2: K*SCL)
  const unsigned short* AuxB = AUXT + (size_t)h64 * 2048;

  #pragma unroll
  for (int i = 0; i < 2; i++) {             // persistent block
    int c = i * 256 + tid, row = c >> 3, sl = ((c & 7) ^ (row & 7)) << 3;
    __builtin_amdgcn_global_load_lds((glb_u32*)(CKQ + (size_t)(p0 + row) * 2048 + cB + sl),
        (lds_u32*)((char*)Pblk + i * 4096 + wave * 1024), 16, 0, 0);
  }
  auto stage = [&](unsigned short* bufI, unsigned short* bufX, int i0) {
    #pragma unroll
    for (int i = 0; i < 2; i++) {
      int c = i * 256 + tid, row = c >> 3, sl = ((c & 7) ^ (row & 7)) << 3;
      __builtin_amdgcn_global_load_lds((glb_u32*)(CKQ + (size_t)(i0 + row) * 2048 + cA + sl),
          (lds_u32*)((char*)bufI + i * 4096 + wave * 1024), 16, 0, 0);
    }
    #pragma unroll
    for (int i = 0; i < 2; i++) {
      int c = i * 256 + tid, row = c >> 3, sl = ((c & 7) ^ (row & 7)) << 3;
      __builtin_amdgcn_global_load_lds((glb_u32*)(AuxB + (size_t)row * 2048 + i0 + sl),
          (lds_u32*)((char*)bufX + i * 4096 + wave * 1024), 16, 0, 0);
    }
  };
  stage(Ain[0], Auxs[0], 0);
  stage(Ain[1], Auxs[1], 64);
  if (tid < 64) L_lds[tid] = 0.f;
  wait_vm_lgkm0<4>();                        // persist + tile0 landed; tile1 in flight
  __builtin_amdgcn_s_barrier();

  // hoist persistent-block B fragments to registers (read Pblk once)
  bf16x8 bs[2][2];
  #pragma unroll
  for (int k2 = 0; k2 < 2; k2++)
    #pragma unroll
    for (int n = 0; n < 2; n++)
      bs[k2][n] = ldswz(Pblk, wc * 32 + n * 16 + lrow, k2, g);

  bf16x8 ones;
  #pragma unroll
  for (int i = 0; i < 8; i++) ones[i] = (short)0x3F80;   // bf16 1.0

  f32x4 acc_pv[2][2] = {};
  f32x4 acc_L[2] = {};
  int bc = 0;
  for (int t = 0; t < 32; t++) {
    int bp = bc + 2; if (bp >= 3) bp -= 3;
    if (t + 2 < 32) stage(Ain[bp], Auxs[bp], (t + 2) * 64);
    const unsigned short* AinC = Ain[bc];
    const unsigned short* AuxC = Auxs[bc];
    // ---- S-GEMM: acc_s[m][n]: row = inner (wr*32+m*16+4g+j), col = persist (wc*32+n*16+lrow)
    f32x4 acc_s[2][2] = {};
    __builtin_amdgcn_s_setprio(1);
    #pragma unroll
    for (int k2 = 0; k2 < 2; k2++) {
      bf16x8 a_[2];
      #pragma unroll
      for (int m = 0; m < 2; m++) a_[m] = ldswz(AinC, wr * 32 + m * 16 + lrow, k2, g);
      #pragma unroll
      for (int m = 0; m < 2; m++)
        #pragma unroll
        for (int n = 0; n < 2; n++)
          acc_s[m][n] = __builtin_amdgcn_mfma_f32_16x16x32_bf16(a_[m], bs[k2][n], acc_s[m][n], 0, 0, 0);
    }
    __builtin_amdgcn_s_setprio(0);
    // ---- exp2 (K pre-scaled by beta*log2e) + cvt_pk pack + Plds write + L-MFMA
    #pragma unroll
    for (int n = 0; n < 2; n++) {
      int p = wc * 32 + n * 16 + lrow;
      uint32_t w4[4];
      #pragma unroll
      for (int m = 0; m < 2; m++) {
        float e0 = exp2f(acc_s[m][n][0]);
        float e1 = exp2f(acc_s[m][n][1]);
        float e2 = exp2f(acc_s[m][n][2]);
        float e3 = exp2f(acc_s[m][n][3]);
        uint32_t lo, hi;
        asm("v_cvt_pk_bf16_f32 %0, %1, %2" : "=v"(lo) : "v"(e0), "v"(e1));
        asm("v_cvt_pk_bf16_f32 %0, %1, %2" : "=v"(hi) : "v"(e2), "v"(e3));
        w4[m * 2] = lo; w4[m * 2 + 1] = hi;
        int i0l = wr * 32 + m * 16 + 4 * g, slb = i0l >> 3;
        uint2 wv; wv.x = lo; wv.y = hi;
        *(uint2*)((char*)Plds + p * 128 + ((slb ^ (p & 7)) << 4) + (g & 1) * 8) = wv;
      }
      if (DIV) {   // L row-sums via MFMA against ones (k-order irrelevant for a sum)
        union { bf16x8 v; uint32_t w[4]; } u;
        u.w[0] = w4[0]; u.w[1] = w4[1]; u.w[2] = w4[2]; u.w[3] = w4[3];
        acc_L[n] = __builtin_amdgcn_mfma_f32_16x16x32_bf16(u.v, ones, acc_L[n], 0, 0, 0);
      }
    }
    asm volatile("s_waitcnt lgkmcnt(0)" ::: "memory");   // Plds visible; prefetch stays in flight
    __builtin_amdgcn_sched_barrier(0);
    __builtin_amdgcn_s_barrier();
    // ---- PV-GEMM: acc_pv[m][n]: row = persist (wr*32+m*16+4g+j), col = z (wc*32+n*16+lrow)
    __builtin_amdgcn_s_setprio(1);
    #pragma unroll
    for (int k2 = 0; k2 < 2; k2++) {
      bf16x8 pa[2], pb[2];
      #pragma unroll
      for (int m = 0; m < 2; m++) pa[m] = ldswz(Plds, wr * 32 + m * 16 + lrow, k2, g);
      #pragma unroll
      for (int n = 0; n < 2; n++) pb[n] = ldswz(AuxC, wc * 32 + n * 16 + lrow, k2, g);
      #pragma unroll
      for (int m = 0; m < 2; m++)
        #pragma unroll
        for (int n = 0; n < 2; n++)
          acc_pv[m][n] = __builtin_amdgcn_mfma_f32_16x16x32_bf16(pa[m], pb[n], acc_pv[m][n], 0, 0, 0);
    }
    __builtin_amdgcn_s_setprio(0);
    if (t + 2 < 32) wait_vm_lgkm0<4>(); else wait_vm_lgkm0<0>();
    __builtin_amdgcn_s_barrier();
    bc = (bc == 2) ? 0 : bc + 1;
  }
  // ---- L reduction (F1): acc_L[n][j] holds rowsum for persist wc*32+n*16+4g+j (all lrow copies)
  if (DIV && lrow == 0) {
    #pragma unroll
    for (int n = 0; n < 2; n++)
      #pragma unroll
      for (int j = 0; j < 4; j++)
        atomicAdd(&L_lds[wc * 32 + n * 16 + 4 * g + j], acc_L[n][j]);
  }
  __syncthreads();
  if (DIV && tid < 64) Lg[(size_t)h * NT + p0 + tid] = L_lds[tid];
  int cbase = DIV ? h64 : TD + h64;
  #pragma unroll
  for (int m = 0; m < 2; m++) {
    int pr = wr * 32 + m * 16 + 4 * g;
    #pragma unroll
    for (int n = 0; n < 2; n++) {
      int z = wc * 32 + n * 16 + lrow;
      f32x4 v = acc_pv[m][n];
      #pragma unroll
      for (int j = 0; j < 4; j++) {
        float x = v[j];
        if (DIV) x /= L_lds[pr + j];
        C[(size_t)(p0 + pr + j) * 2048 + cbase + z] = f2bf(x);
      }
    }
  }
}

// ------------------------------------------------------------------
extern "C" void kernel_launch(void* const* d_in, const int* in_sizes, int n_in,
                              void* d_out, int out_size, void* d_ws, size_t ws_size,
                              hipStream_t stream)
{
  (void)in_sizes; (void)n_in; (void)out_size; (void)ws_size;
  const float* g  = (const float*)d_in[0];
  const float* Wk = (const float*)d_in[1];
  const float* Wq = (const float*)d_in[2];

  char* ws = (char*)d_ws;
  size_t off = 0;
  auto alloc = [&](size_t b) -> char* {
    char* p = ws + off; off += (b + 255) & ~((size_t)255); return p;
  };
  unsigned short* gbf  = (unsigned short*)alloc((size_t)NT * TD * 2);     // 4 MB
  unsigned short* wkq  = (unsigned short*)alloc((size_t)2 * TD * TD * 2); // 4 MB
  unsigned short* twqk = (unsigned short*)alloc((size_t)TD * 2048 * 2);   // 4 MB
  unsigned short* CKQ  = (unsigned short*)alloc((size_t)NT * 2048 * 2);   // 8 MB
  unsigned short* TKQ  = (unsigned short*)alloc((size_t)NT * 2048 * 2);   // 8 MB
  unsigned short* CB12 = (unsigned short*)alloc((size_t)NT * 2048 * 2);   // 8 MB
  unsigned short* QsT  = (unsigned short*)alloc((size_t)TD * NT * 2);     // 4 MB
  float*          Lbuf = (float*)alloc((size_t)NH * NT * 4);              // 128 KB

  prep_kernel<<<dim3(4096), dim3(256), 0, stream>>>(g, Wk, Wq, gbf, wkq, twqk);

  // K,Q = g * [Wk;Wq]^T -> CKQ [tok][2048] (K cols scaled by SCL), TKQ = CKQ^T unscaled
  btg2_kernel<128, 64, 0><<<dim3(16, 32), dim3(256), 0, stream>>>(
      gbf, TD, wkq, TD, TD, (void*)CKQ, (void*)TKQ);

  // F1: B1 (normalized) -> CB12 cols [h*64, h*64+64), plus L
  fused_kernel<true><<<dim3(32, NH), dim3(256), 0, stream>>>(CKQ, TKQ, CB12, Lbuf);

  // Qn^T = Q^T / L
  qst_kernel<<<dim3(1024), dim3(256), 0, stream>>>(TKQ, Lbuf, QsT);

  // F2: B2 -> CB12 cols [1024+h*64, ...)
  fused_kernel<false><<<dim3(32, NH), dim3(256), 0, stream>>>(CKQ, QsT, CB12, nullptr);

  // out = -( CB12 * twqk^T )   (f32)
  btg2_kernel<64, 64, 4><<<dim3(32, 16), dim3(256), 0, stream>>>(
      CB12, 2048, twqk, 2048, 2048, d_out, nullptr);
}

// Round 5
// 122.400 us; speedup vs baseline: 1.1134x; 1.1134x over previous
//
#include <hip/hip_runtime.h>
#include <stdint.h>

#define NT 2048     // tokens
#define TD 1024     // token dim
#define NH 16       // heads
static constexpr float SCL = 0.18033688011112042f;  // beta*log2(e), folded into K cols

typedef __attribute__((ext_vector_type(8))) short bf16x8;
typedef __attribute__((ext_vector_type(4))) float f32x4;
typedef __attribute__((address_space(3))) uint32_t lds_u32;
typedef __attribute__((address_space(1))) uint32_t glb_u32;

__device__ __forceinline__ float bf2f(unsigned short u){
  union { uint32_t u32; float f; } v; v.u32 = ((uint32_t)u) << 16; return v.f;
}
__device__ __forceinline__ unsigned short f2bf(float f){
  union { float f; uint32_t u; } v; v.f = f;
  uint32_t r = v.u + 0x7fffu + ((v.u >> 16) & 1u);   // RNE
  return (unsigned short)(r >> 16);
}
// 128B-row tile (8x16B slots), phys slot = kc ^ (row&7)
__device__ __forceinline__ bf16x8 ld8(const unsigned short* base, int row, int kc){
  return *(const bf16x8*)((const char*)base + row*128 + ((kc ^ (row & 7)) << 4));
}
// 256B-row tile (16x16B slots), phys slot = kc ^ (row&15)
__device__ __forceinline__ bf16x8 ld16(const unsigned short* base, int row, int kc){
  return *(const bf16x8*)((const char*)base + row*256 + ((kc ^ (row & 15)) << 4));
}
template<int N> __device__ __forceinline__ void wait_vm_lgkm0(){
  if constexpr (N == 0)      asm volatile("s_waitcnt vmcnt(0) lgkmcnt(0)" ::: "memory");
  else if constexpr (N == 4) asm volatile("s_waitcnt vmcnt(4) lgkmcnt(0)" ::: "memory");
  else if constexpr (N == 6) asm volatile("s_waitcnt vmcnt(6) lgkmcnt(0)" ::: "memory");
  __builtin_amdgcn_sched_barrier(0);
}

// ------------------------------------------------------------------
// prep: gbf = bf16(g); wkq = bf16([Wk;Wq]) rows hz2 x 1024;
//       twqk[d][j] = j<1024 ? Wq[j][d] : Wk[j-1024][d]  (bf16, 1024x2048)
// ------------------------------------------------------------------
__global__ __launch_bounds__(256) void prep_kernel(
    const float* __restrict__ g, const float* __restrict__ Wk, const float* __restrict__ Wq,
    unsigned short* __restrict__ gbf, unsigned short* __restrict__ wkq,
    unsigned short* __restrict__ twqk)
{
  int b = blockIdx.x;
  if (b < 1024) {
    int base = b * 2048 + threadIdx.x;
    #pragma unroll
    for (int i = 0; i < 8; i++) { int idx = base + i * 256; gbf[idx] = f2bf(g[idx]); }
  } else if (b < 2048) {
    int base = (b - 1024) * 2048 + threadIdx.x;
    #pragma unroll
    for (int i = 0; i < 8; i++) {
      int idx = base + i * 256;
      float v = (idx < (1 << 20)) ? Wk[idx] : Wq[idx - (1 << 20)];
      wkq[idx] = f2bf(v);
    }
  } else {
    int t = b - 2048;                  // 32 d-tiles x 64 j-tiles
    int dt = t & 31, jt = t >> 5;
    __shared__ float tile[32][33];
    int tx = threadIdx.x & 31, ty = threadIdx.x >> 5;
    int j0 = jt * 32, d0 = dt * 32;
    const float* src = (j0 < 1024) ? Wq : Wk;
    int jb = (j0 < 1024) ? j0 : (j0 - 1024);
    #pragma unroll
    for (int rr = 0; rr < 4; rr++)
      tile[ty + rr * 8][tx] = src[(size_t)(jb + ty + rr * 8) * 1024 + d0 + tx];
    __syncthreads();
    #pragma unroll
    for (int rr = 0; rr < 4; rr++)
      twqk[(size_t)(d0 + ty + rr * 8) * 2048 + j0 + tx] = f2bf(tile[tx][ty + rr * 8]);
  }
}

// ------------------------------------------------------------------
// qst: QsT[r][q] = TKQ[1024+r][q] / L[r>>6][q]
// ------------------------------------------------------------------
__global__ __launch_bounds__(256) void qst_kernel(const unsigned short* __restrict__ tkq,
                                                  const float* __restrict__ L,
                                                  unsigned short* __restrict__ qst)
{
  int r = blockIdx.x;
  int h = r >> 6;
  const unsigned short* src = tkq + (size_t)(1024 + r) * 2048;
  unsigned short* dst = qst + (size_t)r * 2048;
  const float* Lh = L + (size_t)h * NT;
  for (int q = threadIdx.x; q < NT; q += 256)
    dst[q] = f2bf(bf2f(src[q]) / Lh[q]);
}

// ------------------------------------------------------------------
// btg2: C = A[M x K] * BT[N x K]^T, bf16, BK=64, triple-buffered counted vmcnt.
// EPI 0: C0 = bf16 C (ld 2048), K-cols (bn<1024) pre-scaled by SCL;
//        C1 = transposed bf16 (ld 2048), UNSCALED                    [KQ]
// EPI 4: C0 f32 [r][1024] = -acc                                     [out]
// ------------------------------------------------------------------
template<int TM, int TN, int EPI>
__global__ __launch_bounds__(256, 2) void btg2_kernel(
    const unsigned short* __restrict__ A, int lda,
    const unsigned short* __restrict__ BT, int ldb,
    int Kdim, void* C0, void* C1)
{
  constexpr int WM = TM / 2, WN = TN / 2, FM = WM / 16, FN = WN / 16;
  constexpr int AC = TM / 32, BC = TN / 32, LOADS = AC + BC;
  __shared__ __align__(16) unsigned short As[3][TM * 64];
  __shared__ __align__(16) unsigned short Bs[3][TN * 64];
  int tid = threadIdx.x, lane = tid & 63, wave = tid >> 6;
  int wr = wave >> 1, wc = wave & 1, lrow = lane & 15, g = lane >> 4;
  int bm = blockIdx.x * TM, bn = blockIdx.y * TN;

  auto stage = [&](unsigned short* bufA, unsigned short* bufB, int kk) {
    #pragma unroll
    for (int i = 0; i < AC; i++) {
      int c = i * 256 + tid, row = c >> 3, sl = ((c & 7) ^ (row & 7)) << 3;
      __builtin_amdgcn_global_load_lds((glb_u32*)(A + (size_t)(bm + row) * lda + kk + sl),
          (lds_u32*)((char*)bufA + i * 4096 + wave * 1024), 16, 0, 0);
    }
    #pragma unroll
    for (int i = 0; i < BC; i++) {
      int c = i * 256 + tid, row = c >> 3, sl = ((c & 7) ^ (row & 7)) << 3;
      __builtin_amdgcn_global_load_lds((glb_u32*)(BT + (size_t)(bn + row) * ldb + kk + sl),
          (lds_u32*)((char*)bufB + i * 4096 + wave * 1024), 16, 0, 0);
    }
  };

  f32x4 acc[FM][FN] = {};
  int nt = Kdim >> 6;
  stage(As[0], Bs[0], 0);
  stage(As[1], Bs[1], 64);
  wait_vm_lgkm0<LOADS>();          // tile0 landed; tile1 still in flight
  __builtin_amdgcn_s_barrier();
  int bc = 0;
  for (int t = 0; t < nt; t++) {
    int bp = bc + 2; if (bp >= 3) bp -= 3;
    if (t + 2 < nt) stage(As[bp], Bs[bp], (t + 2) * 64);
    const unsigned short* Ac = As[bc];
    const unsigned short* Bc = Bs[bc];
    #pragma unroll
    for (int k2 = 0; k2 < 2; k2++) {
      bf16x8 a_[FM], b_[FN];
      #pragma unroll
      for (int m = 0; m < FM; m++) a_[m] = ld8(Ac, wr * WM + m * 16 + lrow, k2 * 4 + g);
      #pragma unroll
      for (int n = 0; n < FN; n++) b_[n] = ld8(Bc, wc * WN + n * 16 + lrow, k2 * 4 + g);
      #pragma unroll
      for (int m = 0; m < FM; m++)
        #pragma unroll
        for (int n = 0; n < FN; n++)
          acc[m][n] = __builtin_amdgcn_mfma_f32_16x16x32_bf16(a_[m], b_[n], acc[m][n], 0, 0, 0);
    }
    if (t + 2 < nt) wait_vm_lgkm0<LOADS>(); else wait_vm_lgkm0<0>();
    __builtin_amdgcn_s_barrier();
    bc = (bc == 2) ? 0 : bc + 1;
  }
  #pragma unroll
  for (int m = 0; m < FM; m++) {
    int rb = bm + wr * WM + m * 16 + 4 * g;
    #pragma unroll
    for (int n = 0; n < FN; n++) {
      int cc = bn + wc * WN + n * 16 + lrow;
      f32x4 v = acc[m][n];
      if constexpr (EPI == 0) {
        unsigned short* Cp = (unsigned short*)C0;
        unsigned short* T  = (unsigned short*)C1;
        float sc = (bn < 1024) ? SCL : 1.0f;   // pre-scale K features for exp2 path
        unsigned short pt[4];
        #pragma unroll
        for (int j = 0; j < 4; j++) {
          pt[j] = f2bf(v[j]);
          Cp[(size_t)(rb + j) * 2048 + cc] = f2bf(v[j] * sc);
        }
        ushort4 t4; t4.x = pt[0]; t4.y = pt[1]; t4.z = pt[2]; t4.w = pt[3];
        *(ushort4*)(T + (size_t)cc * 2048 + rb) = t4;
      } else {
        float* Cf = (float*)C0;
        #pragma unroll
        for (int j = 0; j < 4; j++) Cf[(size_t)(rb + j) * 1024 + cc] = -v[j];
      }
    }
  }
}

// ------------------------------------------------------------------
// fused flash kernel, restructured for latency amortization:
//  - inner tile 128, 16 iterations, ONE barrier per iteration
//  - 4 waves: wr = inner-64 half, wc = persist-32 half; 32 MFMA/wave/iter
//  - PV is wave-local (each wave contracts its own inner-64 via its own Plds
//    slice: write + lgkm + read, no cross-wave barrier)
//  - cross-wave (wr) PV reduction once at the end via LDS tree in retired bufs
// LDS pool (80 KB -> exactly 2 blocks/CU):
//   0:     Ain[0] 16K   (128 rows x 64 cols, 8 slots/row, ^(row&7))
//   16384: Ain[1] 16K
//   32768: Aux[0] 16K   (64 z-rows x 128 cols, 16 slots/row, ^(row&15))
//   49152: Aux[1] 16K
//   65536: PB 8K (64x64, ^(row&7)) -> reused as Plds (4K/wave: 32x64, ^(pl&7))
//          -> L_lds aliases +65536 after loop. Red[wr][wc][32][64] f32 = 64K
//          overlays bytes 0..65536 after loop.
// ------------------------------------------------------------------
template<bool DIV>
__global__ __launch_bounds__(256, 2) void fused_kernel(
    const unsigned short* __restrict__ CKQ,   // [2048][2048]: K*SCL cols 0:1024, Q cols 1024:2048
    const unsigned short* __restrict__ AUXT,  // TKQ (F1, unscaled K^T) or QsT (F2): rows h*64+z
    unsigned short* __restrict__ C,           // CB12 [2048][2048]
    float* __restrict__ Lg)                   // [16][2048] (F1 only)
{
  __shared__ __align__(16) char pool[81920];
  unsigned short* PB = (unsigned short*)(pool + 65536);
  float* Red   = (float*)pool;
  float* L_lds = (float*)(pool + 65536);

  int tid = threadIdx.x, lane = tid & 63, wave = tid >> 6;
  int wr = wave >> 1, wc = wave & 1, lrow = lane & 15, g = lane >> 4;
  int p0 = blockIdx.x * 64, h = blockIdx.y, h64 = h * 64;
  int cA = DIV ? h64 : TD + h64;            // inner-tile cols (F1: K*SCL, F2: Q)
  int cB = DIV ? TD + h64 : h64;            // persistent cols (F1: Q, F2: K*SCL)
  const unsigned short* AuxG = AUXT + (size_t)h64 * 2048;

  auto stageAin = [&](char* dst, int i0) {   // 128x64 tile, 4 chunks/thread
    #pragma unroll
    for (int i = 0; i < 4; i++) {
      int c = i * 256 + tid, row = c >> 3, scol = ((c & 7) ^ (row & 7)) << 3;
      __builtin_amdgcn_global_load_lds((glb_u32*)(CKQ + (size_t)(i0 + row) * 2048 + cA + scol),
          (lds_u32*)(dst + i * 4096 + wave * 1024), 16, 0, 0);
    }
  };
  auto stageAux = [&](char* dst, int i0) {   // 64x128 tile, 4 chunks/thread
    #pragma unroll
    for (int i = 0; i < 4; i++) {
      int c = i * 256 + tid, row = c >> 4, scol = ((c & 15) ^ (row & 15)) << 3;
      __builtin_amdgcn_global_load_lds((glb_u32*)(AuxG + (size_t)row * 2048 + i0 + scol),
          (lds_u32*)(dst + i * 4096 + wave * 1024), 16, 0, 0);
    }
  };

  // prologue: stage PB + tile0
  #pragma unroll
  for (int i = 0; i < 2; i++) {
    int c = i * 256 + tid, row = c >> 3, scol = ((c & 7) ^ (row & 7)) << 3;
    __builtin_amdgcn_global_load_lds((glb_u32*)(CKQ + (size_t)(p0 + row) * 2048 + cB + scol),
        (lds_u32*)((char*)PB + i * 4096 + wave * 1024), 16, 0, 0);
  }
  stageAin(pool, 0);
  stageAux(pool + 32768, 0);
  wait_vm_lgkm0<0>();
  __builtin_amdgcn_s_barrier();

  // hoist persistent fragments (persist rows wc*32 + n*16 + lrow, k = 64)
  bf16x8 bs[2][2];
  #pragma unroll
  for (int k2 = 0; k2 < 2; k2++)
    #pragma unroll
    for (int n = 0; n < 2; n++)
      bs[k2][n] = ld8(PB, wc * 32 + n * 16 + lrow, k2 * 4 + g);
  __syncthreads();   // all hoists done before Plds overwrites PB region

  unsigned short* PldsW = (unsigned short*)(pool + 65536 + wave * 4096); // [32 pl][64 il]
  f32x4 acc_pv[2][4] = {};
  float lsum[2] = {0.f, 0.f};

  for (int t = 0; t < 16; t++) {
    const unsigned short* curA = (const unsigned short*)(pool + (t & 1) * 16384);
    const unsigned short* curX = (const unsigned short*)(pool + 32768 + (t & 1) * 16384);
    if (t + 1 < 16) {
      stageAin(pool + ((t + 1) & 1) * 16384, (t + 1) * 128);
      stageAux(pool + 32768 + ((t + 1) & 1) * 16384, (t + 1) * 128);
    }
    // ---- S-GEMM: wave's inner-64 (wr) x persist-32 (wc), k=64
    f32x4 acc_s[4][2] = {};
    __builtin_amdgcn_s_setprio(1);
    #pragma unroll
    for (int k2 = 0; k2 < 2; k2++) {
      bf16x8 a_[4];
      #pragma unroll
      for (int m = 0; m < 4; m++) a_[m] = ld8(curA, wr * 64 + m * 16 + lrow, k2 * 4 + g);
      #pragma unroll
      for (int m = 0; m < 4; m++)
        #pragma unroll
        for (int n = 0; n < 2; n++)
          acc_s[m][n] = __builtin_amdgcn_mfma_f32_16x16x32_bf16(a_[m], bs[k2][n], acc_s[m][n], 0, 0, 0);
    }
    __builtin_amdgcn_s_setprio(0);
    // ---- exp2 + pack -> wave-local Plds [pl = n*16+lrow][il = m*16+4g+j]
    #pragma unroll
    for (int n = 0; n < 2; n++) {
      int pl = n * 16 + lrow;
      #pragma unroll
      for (int m = 0; m < 4; m++) {
        float e0 = exp2f(acc_s[m][n][0]);
        float e1 = exp2f(acc_s[m][n][1]);
        float e2 = exp2f(acc_s[m][n][2]);
        float e3 = exp2f(acc_s[m][n][3]);
        if (DIV) lsum[n] += (e0 + e1) + (e2 + e3);
        uint32_t lo, hi;
        asm("v_cvt_pk_bf16_f32 %0, %1, %2" : "=v"(lo) : "v"(e0), "v"(e1));
        asm("v_cvt_pk_bf16_f32 %0, %1, %2" : "=v"(hi) : "v"(e2), "v"(e3));
        uint2 wv; wv.x = lo; wv.y = hi;   // il-chunk m*16+4g.. at 8B unit u=m*4+g
        *(uint2*)((char*)PldsW + pl * 128 + ((((m * 2) + (g >> 1)) ^ (pl & 7)) << 4) + (g & 1) * 8) = wv;
      }
    }
    // ---- PV (wave-local): persist-32 x z-64, contract wave's inner-64
    __builtin_amdgcn_s_setprio(1);
    #pragma unroll
    for (int k2p = 0; k2p < 2; k2p++) {
      bf16x8 pa[2], pb[4];
      #pragma unroll
      for (int m2 = 0; m2 < 2; m2++) pa[m2] = ld8(PldsW, m2 * 16 + lrow, k2p * 4 + g);
      #pragma unroll
      for (int n4 = 0; n4 < 4; n4++) pb[n4] = ld16(curX, n4 * 16 + lrow, wr * 8 + k2p * 4 + g);
      #pragma unroll
      for (int m2 = 0; m2 < 2; m2++)
        #pragma unroll
        for (int n4 = 0; n4 < 4; n4++)
          acc_pv[m2][n4] = __builtin_amdgcn_mfma_f32_16x16x32_bf16(pa[m2], pb[n4], acc_pv[m2][n4], 0, 0, 0);
    }
    __builtin_amdgcn_s_setprio(0);
    wait_vm_lgkm0<0>();
    __builtin_amdgcn_s_barrier();
  }

  // ---- end: Red writes (overlay staging bufs) + L
  #pragma unroll
  for (int m2 = 0; m2 < 2; m2++)
    #pragma unroll
    for (int n4 = 0; n4 < 4; n4++) {
      #pragma unroll
      for (int j = 0; j < 4; j++) {
        int pl = m2 * 16 + 4 * g + j, z = n4 * 16 + lrow;
        Red[(size_t)((wr * 2 + wc) * 32 + pl) * 64 + z] = acc_pv[m2][n4][j];
      }
    }
  if (DIV && tid < 64) L_lds[tid] = 0.f;
  __syncthreads();
  if (DIV) {
    float s0 = lsum[0], s1 = lsum[1];
    s0 += __shfl_xor(s0, 16); s0 += __shfl_xor(s0, 32);
    s1 += __shfl_xor(s1, 16); s1 += __shfl_xor(s1, 32);
    if (lane < 16) {
      atomicAdd(&L_lds[wc * 32 + lrow], s0);
      atomicAdd(&L_lds[wc * 32 + 16 + lrow], s1);
    }
    __syncthreads();
    if (tid < 64) Lg[(size_t)h * NT + p0 + tid] = L_lds[tid];
  }
  // output: thread -> persist row pr = tid>>2, z-range (tid&3)*16
  int pr = tid >> 2, zb = (tid & 3) * 16;
  int wcr = pr >> 5, pl = pr & 31;
  float inv = (DIV) ? 1.0f / L_lds[pr] : 1.0f;
  int cbase = DIV ? h64 : TD + h64;
  unsigned short ob[16];
  #pragma unroll
  for (int zz = 0; zz < 16; zz += 4) {
    f32x4 s0 = *(f32x4*)&Red[(size_t)((0 * 2 + wcr) * 32 + pl) * 64 + zb + zz];
    f32x4 s1 = *(f32x4*)&Red[(size_t)((1 * 2 + wcr) * 32 + pl) * 64 + zb + zz];
    #pragma unroll
    for (int j = 0; j < 4; j++) ob[zz + j] = f2bf((s0[j] + s1[j]) * inv);
  }
  unsigned short* dst = C + (size_t)(p0 + pr) * 2048 + cbase + zb;
  *(ushort4*)dst = *(ushort4*)&ob[0];
  *(ushort4*)(dst + 4) = *(ushort4*)&ob[4];
  *(ushort4*)(dst + 8) = *(ushort4*)&ob[8];
  *(ushort4*)(dst + 12) = *(ushort4*)&ob[12];
}

// ------------------------------------------------------------------
extern "C" void kernel_launch(void* const* d_in, const int* in_sizes, int n_in,
                              void* d_out, int out_size, void* d_ws, size_t ws_size,
                              hipStream_t stream)
{
  (void)in_sizes; (void)n_in; (void)out_size; (void)ws_size;
  const float* g  = (const float*)d_in[0];
  const float* Wk = (const float*)d_in[1];
  const float* Wq = (const float*)d_in[2];

  char* ws = (char*)d_ws;
  size_t off = 0;
  auto alloc = [&](size_t b) -> char* {
    char* p = ws + off; off += (b + 255) & ~((size_t)255); return p;
  };
  unsigned short* gbf  = (unsigned short*)alloc((size_t)NT * TD * 2);     // 4 MB
  unsigned short* wkq  = (unsigned short*)alloc((size_t)2 * TD * TD * 2); // 4 MB
  unsigned short* twqk = (unsigned short*)alloc((size_t)TD * 2048 * 2);   // 4 MB
  unsigned short* CKQ  = (unsigned short*)alloc((size_t)NT * 2048 * 2);   // 8 MB
  unsigned short* TKQ  = (unsigned short*)alloc((size_t)NT * 2048 * 2);   // 8 MB
  unsigned short* CB12 = (unsigned short*)alloc((size_t)NT * 2048 * 2);   // 8 MB
  unsigned short* QsT  = (unsigned short*)alloc((size_t)TD * NT * 2);     // 4 MB
  float*          Lbuf = (float*)alloc((size_t)NH * NT * 4);              // 128 KB

  prep_kernel<<<dim3(4096), dim3(256), 0, stream>>>(g, Wk, Wq, gbf, wkq, twqk);

  // K,Q = g * [Wk;Wq]^T -> CKQ [tok][2048] (K cols scaled by SCL), TKQ = CKQ^T unscaled
  btg2_kernel<128, 64, 0><<<dim3(16, 32), dim3(256), 0, stream>>>(
      gbf, TD, wkq, TD, TD, (void*)CKQ, (void*)TKQ);

  // F1: B1 (normalized) -> CB12 cols [h*64, h*64+64), plus L
  fused_kernel<true><<<dim3(32, NH), dim3(256), 0, stream>>>(CKQ, TKQ, CB12, Lbuf);

  // Qn^T = Q^T / L
  qst_kernel<<<dim3(1024), dim3(256), 0, stream>>>(TKQ, Lbuf, QsT);

  // F2: B2 -> CB12 cols [1024+h*64, ...)
  fused_kernel<false><<<dim3(32, NH), dim3(256), 0, stream>>>(CKQ, QsT, CB12, nullptr);

  // out = -( CB12 * twqk^T )   (f32)
  btg2_kernel<64, 64, 4><<<dim3(32, 16), dim3(256), 0, stream>>>(
      CB12, 2048, twqk, 2048, 2048, d_out, nullptr);
}

// Round 6
// 120.567 us; speedup vs baseline: 1.1304x; 1.0152x over previous
//
#include <hip/hip_runtime.h>
#include <stdint.h>

#define NT 2048     // tokens
#define TD 1024     // token dim
#define NH 16       // heads
static constexpr float SCL = 0.18033688011112042f;  // beta*log2(e), folded into K cols

typedef __attribute__((ext_vector_type(8))) short bf16x8;
typedef __attribute__((ext_vector_type(4))) float f32x4;
typedef __attribute__((address_space(3))) uint32_t lds_u32;
typedef __attribute__((address_space(1))) uint32_t glb_u32;

__device__ __forceinline__ float bf2f(unsigned short u){
  union { uint32_t u32; float f; } v; v.u32 = ((uint32_t)u) << 16; return v.f;
}
__device__ __forceinline__ unsigned short f2bf(float f){
  union { float f; uint32_t u; } v; v.f = f;
  uint32_t r = v.u + 0x7fffu + ((v.u >> 16) & 1u);   // RNE
  return (unsigned short)(r >> 16);
}
// 128B-row tile (8x16B slots), phys slot = kc ^ (row&7)
__device__ __forceinline__ bf16x8 ld8(const unsigned short* base, int row, int kc){
  return *(const bf16x8*)((const char*)base + row*128 + ((kc ^ (row & 7)) << 4));
}
// 256B-row tile (16x16B slots), phys slot = kc ^ (row&15)
__device__ __forceinline__ bf16x8 ld16(const unsigned short* base, int row, int kc){
  return *(const bf16x8*)((const char*)base + row*256 + ((kc ^ (row & 15)) << 4));
}
template<int N> __device__ __forceinline__ void wait_vm_lgkm0(){
  if constexpr (N == 0)      asm volatile("s_waitcnt vmcnt(0) lgkmcnt(0)" ::: "memory");
  else if constexpr (N == 4) asm volatile("s_waitcnt vmcnt(4) lgkmcnt(0)" ::: "memory");
  else if constexpr (N == 6) asm volatile("s_waitcnt vmcnt(6) lgkmcnt(0)" ::: "memory");
  __builtin_amdgcn_sched_barrier(0);
}

// ------------------------------------------------------------------
// prep: gbf = bf16(g); wkq = bf16([Wk;Wq]) rows hz2 x 1024;
//       twqk[d][j] = j<1024 ? Wq[j][d] : Wk[j-1024][d]  (bf16, 1024x2048)
// ------------------------------------------------------------------
__global__ __launch_bounds__(256) void prep_kernel(
    const float* __restrict__ g, const float* __restrict__ Wk, const float* __restrict__ Wq,
    unsigned short* __restrict__ gbf, unsigned short* __restrict__ wkq,
    unsigned short* __restrict__ twqk)
{
  int b = blockIdx.x;
  if (b < 1024) {
    int base = b * 2048 + threadIdx.x;
    #pragma unroll
    for (int i = 0; i < 8; i++) { int idx = base + i * 256; gbf[idx] = f2bf(g[idx]); }
  } else if (b < 2048) {
    int base = (b - 1024) * 2048 + threadIdx.x;
    #pragma unroll
    for (int i = 0; i < 8; i++) {
      int idx = base + i * 256;
      float v = (idx < (1 << 20)) ? Wk[idx] : Wq[idx - (1 << 20)];
      wkq[idx] = f2bf(v);
    }
  } else {
    int t = b - 2048;                  // 32 d-tiles x 64 j-tiles
    int dt = t & 31, jt = t >> 5;
    __shared__ float tile[32][33];
    int tx = threadIdx.x & 31, ty = threadIdx.x >> 5;
    int j0 = jt * 32, d0 = dt * 32;
    const float* src = (j0 < 1024) ? Wq : Wk;
    int jb = (j0 < 1024) ? j0 : (j0 - 1024);
    #pragma unroll
    for (int rr = 0; rr < 4; rr++)
      tile[ty + rr * 8][tx] = src[(size_t)(jb + ty + rr * 8) * 1024 + d0 + tx];
    __syncthreads();
    #pragma unroll
    for (int rr = 0; rr < 4; rr++)
      twqk[(size_t)(d0 + ty + rr * 8) * 2048 + j0 + tx] = f2bf(tile[tx][ty + rr * 8]);
  }
}

// ------------------------------------------------------------------
// qst: QsT[r][q] = TKQ[1024+r][q] / L[r>>6][q]
// ------------------------------------------------------------------
__global__ __launch_bounds__(256) void qst_kernel(const unsigned short* __restrict__ tkq,
                                                  const float* __restrict__ L,
                                                  unsigned short* __restrict__ qst)
{
  int r = blockIdx.x;
  int h = r >> 6;
  const unsigned short* src = tkq + (size_t)(1024 + r) * 2048;
  unsigned short* dst = qst + (size_t)r * 2048;
  const float* Lh = L + (size_t)h * NT;
  for (int q = threadIdx.x; q < NT; q += 256)
    dst[q] = f2bf(bf2f(src[q]) / Lh[q]);
}

// ------------------------------------------------------------------
// btg2: C = A[M x K] * BT[N x K]^T, bf16, BK=64, triple-buffered counted vmcnt.
// EPI 0: C0 = bf16 C (ld 2048), K-cols (bn<1024) pre-scaled by SCL;
//        C1 = transposed bf16 (ld 2048), UNSCALED                    [KQ]
// EPI 4: C0 f32 [r][1024] = -acc                                     [out]
// ------------------------------------------------------------------
template<int TM, int TN, int EPI, int WPE>
__global__ __launch_bounds__(256, WPE) void btg2_kernel(
    const unsigned short* __restrict__ A, int lda,
    const unsigned short* __restrict__ BT, int ldb,
    int Kdim, void* C0, void* C1)
{
  constexpr int WM = TM / 2, WN = TN / 2, FM = WM / 16, FN = WN / 16;
  constexpr int AC = TM / 32, BC = TN / 32, LOADS = AC + BC;
  __shared__ __align__(16) unsigned short As[3][TM * 64];
  __shared__ __align__(16) unsigned short Bs[3][TN * 64];
  int tid = threadIdx.x, lane = tid & 63, wave = tid >> 6;
  int wr = wave >> 1, wc = wave & 1, lrow = lane & 15, g = lane >> 4;
  int bm = blockIdx.x * TM, bn = blockIdx.y * TN;

  auto stage = [&](unsigned short* bufA, unsigned short* bufB, int kk) {
    #pragma unroll
    for (int i = 0; i < AC; i++) {
      int c = i * 256 + tid, row = c >> 3, sl = ((c & 7) ^ (row & 7)) << 3;
      __builtin_amdgcn_global_load_lds((glb_u32*)(A + (size_t)(bm + row) * lda + kk + sl),
          (lds_u32*)((char*)bufA + i * 4096 + wave * 1024), 16, 0, 0);
    }
    #pragma unroll
    for (int i = 0; i < BC; i++) {
      int c = i * 256 + tid, row = c >> 3, sl = ((c & 7) ^ (row & 7)) << 3;
      __builtin_amdgcn_global_load_lds((glb_u32*)(BT + (size_t)(bn + row) * ldb + kk + sl),
          (lds_u32*)((char*)bufB + i * 4096 + wave * 1024), 16, 0, 0);
    }
  };

  f32x4 acc[FM][FN] = {};
  int nt = Kdim >> 6;
  stage(As[0], Bs[0], 0);
  stage(As[1], Bs[1], 64);
  wait_vm_lgkm0<LOADS>();          // tile0 landed; tile1 still in flight
  __builtin_amdgcn_s_barrier();
  int bc = 0;
  for (int t = 0; t < nt; t++) {
    int bp = bc + 2; if (bp >= 3) bp -= 3;
    if (t + 2 < nt) stage(As[bp], Bs[bp], (t + 2) * 64);
    const unsigned short* Ac = As[bc];
    const unsigned short* Bc = Bs[bc];
    #pragma unroll
    for (int k2 = 0; k2 < 2; k2++) {
      bf16x8 a_[FM], b_[FN];
      #pragma unroll
      for (int m = 0; m < FM; m++) a_[m] = ld8(Ac, wr * WM + m * 16 + lrow, k2 * 4 + g);
      #pragma unroll
      for (int n = 0; n < FN; n++) b_[n] = ld8(Bc, wc * WN + n * 16 + lrow, k2 * 4 + g);
      #pragma unroll
      for (int m = 0; m < FM; m++)
        #pragma unroll
        for (int n = 0; n < FN; n++)
          acc[m][n] = __builtin_amdgcn_mfma_f32_16x16x32_bf16(a_[m], b_[n], acc[m][n], 0, 0, 0);
    }
    if (t + 2 < nt) wait_vm_lgkm0<LOADS>(); else wait_vm_lgkm0<0>();
    __builtin_amdgcn_s_barrier();
    bc = (bc == 2) ? 0 : bc + 1;
  }
  #pragma unroll
  for (int m = 0; m < FM; m++) {
    int rb = bm + wr * WM + m * 16 + 4 * g;
    #pragma unroll
    for (int n = 0; n < FN; n++) {
      int cc = bn + wc * WN + n * 16 + lrow;
      f32x4 v = acc[m][n];
      if constexpr (EPI == 0) {
        unsigned short* Cp = (unsigned short*)C0;
        unsigned short* T  = (unsigned short*)C1;
        float sc = (bn < 1024) ? SCL : 1.0f;   // pre-scale K features for exp2 path
        unsigned short pt[4];
        #pragma unroll
        for (int j = 0; j < 4; j++) {
          pt[j] = f2bf(v[j]);
          Cp[(size_t)(rb + j) * 2048 + cc] = f2bf(v[j] * sc);
        }
        ushort4 t4; t4.x = pt[0]; t4.y = pt[1]; t4.z = pt[2]; t4.w = pt[3];
        *(ushort4*)(T + (size_t)cc * 2048 + rb) = t4;
      } else {
        float* Cf = (float*)C0;
        #pragma unroll
        for (int j = 0; j < 4; j++) Cf[(size_t)(rb + j) * 1024 + cc] = -v[j];
      }
    }
  }
}

// ------------------------------------------------------------------
// fused flash kernel, 8-wave / 512-thread version (occupancy: 4 waves/SIMD).
//  - persistent 64 tokens; inner tile 128; 16 iterations; 1 barrier/iter
//  - waves: wr = inner-64 half (wave>>2), wcq = persist-16 quarter (wave&3)
//  - per wave/iter: 8 S-MFMA -> 16 exp2 -> wave-private 2KB Plds -> 8 PV-MFMA
//  - cross-wr PV reduction once at the end via 32KB Red overlay
// LDS pool (80 KB -> exactly 2 blocks/CU):
//   0:     Ain[0] 16K (128r x 64c, 8 slots/row, ^(row&7))
//   16384: Ain[1] 16K
//   32768: Aux[0] 16K (64 z-rows x 128c, 16 slots/row, ^(row&15))   [L_lds post-loop]
//   49152: Aux[1] 16K
//   65536: PB 8K (64x64, ^(row&7)) -> Plds slices (8 x 2K, wave-private)
//   post-loop: Red[2][64][64] f32 = 32K overlays bytes 0..32768
// ------------------------------------------------------------------
template<bool DIV>
__global__ __launch_bounds__(512, 4) void fused_kernel(
    const unsigned short* __restrict__ CKQ,   // [2048][2048]: K*SCL cols 0:1024, Q cols 1024:2048
    const unsigned short* __restrict__ AUXT,  // TKQ (F1, unscaled K^T) or QsT (F2): rows h*64+z
    unsigned short* __restrict__ C,           // CB12 [2048][2048]
    float* __restrict__ Lg)                   // [16][2048] (F1 only)
{
  __shared__ __align__(16) char pool[81920];
  unsigned short* PB = (unsigned short*)(pool + 65536);
  float* Red   = (float*)pool;                 // [2][64][64], post-loop
  float* L_lds = (float*)(pool + 32768);       // post-loop

  int tid = threadIdx.x, lane = tid & 63, wave = tid >> 6;
  int wr = wave >> 2, wcq = wave & 3, lrow = lane & 15, g = lane >> 4;
  int p0 = blockIdx.x * 64, h = blockIdx.y, h64 = h * 64;
  int cA = DIV ? h64 : TD + h64;            // inner-tile cols (F1: K*SCL, F2: Q)
  int cB = DIV ? TD + h64 : h64;            // persistent cols (F1: Q, F2: K*SCL)
  const unsigned short* AuxG = AUXT + (size_t)h64 * 2048;

  auto stageAin = [&](char* dst, int i0) {   // 128x64 tile, 2 chunks/thread
    #pragma unroll
    for (int i = 0; i < 2; i++) {
      int c = i * 512 + tid, row = c >> 3, scol = ((c & 7) ^ (row & 7)) << 3;
      __builtin_amdgcn_global_load_lds((glb_u32*)(CKQ + (size_t)(i0 + row) * 2048 + cA + scol),
          (lds_u32*)(dst + i * 8192 + wave * 1024), 16, 0, 0);
    }
  };
  auto stageAux = [&](char* dst, int i0) {   // 64x128 tile, 2 chunks/thread
    #pragma unroll
    for (int i = 0; i < 2; i++) {
      int c = i * 512 + tid, row = c >> 4, scol = ((c & 15) ^ (row & 15)) << 3;
      __builtin_amdgcn_global_load_lds((glb_u32*)(AuxG + (size_t)row * 2048 + i0 + scol),
          (lds_u32*)(dst + i * 8192 + wave * 1024), 16, 0, 0);
    }
  };

  // prologue: stage PB (1 chunk/thread) + tile0
  { int row = tid >> 3, scol = ((tid & 7) ^ (row & 7)) << 3;
    __builtin_amdgcn_global_load_lds((glb_u32*)(CKQ + (size_t)(p0 + row) * 2048 + cB + scol),
        (lds_u32*)((char*)PB + wave * 1024), 16, 0, 0); }
  stageAin(pool, 0);
  stageAux(pool + 32768, 0);
  wait_vm_lgkm0<0>();
  __builtin_amdgcn_s_barrier();

  // hoist persistent fragments (B rows = persist wcq*16 + lrow)
  bf16x8 bs[2];
  #pragma unroll
  for (int k2 = 0; k2 < 2; k2++)
    bs[k2] = ld8(PB, wcq * 16 + lrow, k2 * 4 + g);
  __syncthreads();   // all hoists done before Plds overwrites PB region

  unsigned short* PldsW = (unsigned short*)(pool + 65536 + wave * 2048); // [16 p][64 il]
  f32x4 acc_pv[4] = {};
  float lsum = 0.f;

  for (int t = 0; t < 16; t++) {
    const unsigned short* curA = (const unsigned short*)(pool + (t & 1) * 16384);
    const unsigned short* curX = (const unsigned short*)(pool + 32768 + (t & 1) * 16384);
    if (t + 1 < 16) {
      stageAin(pool + ((t + 1) & 1) * 16384, (t + 1) * 128);
      stageAux(pool + 32768 + ((t + 1) & 1) * 16384, (t + 1) * 128);
    }
    // ---- S-GEMM: inner-64 (wr) x persist-16 (wcq), k=64
    f32x4 acc_s[4] = {};
    __builtin_amdgcn_s_setprio(1);
    #pragma unroll
    for (int k2 = 0; k2 < 2; k2++) {
      bf16x8 a_[4];
      #pragma unroll
      for (int m = 0; m < 4; m++) a_[m] = ld8(curA, wr * 64 + m * 16 + lrow, k2 * 4 + g);
      #pragma unroll
      for (int m = 0; m < 4; m++)
        acc_s[m] = __builtin_amdgcn_mfma_f32_16x16x32_bf16(a_[m], bs[k2], acc_s[m], 0, 0, 0);
    }
    __builtin_amdgcn_s_setprio(0);
    // ---- exp2 + pack -> wave-private Plds [p_loc = lrow][il = m*16+4g+j]
    #pragma unroll
    for (int m = 0; m < 4; m++) {
      float e0 = exp2f(acc_s[m][0]);
      float e1 = exp2f(acc_s[m][1]);
      float e2 = exp2f(acc_s[m][2]);
      float e3 = exp2f(acc_s[m][3]);
      if (DIV) lsum += (e0 + e1) + (e2 + e3);
      uint32_t lo, hi;
      asm("v_cvt_pk_bf16_f32 %0, %1, %2" : "=v"(lo) : "v"(e0), "v"(e1));
      asm("v_cvt_pk_bf16_f32 %0, %1, %2" : "=v"(hi) : "v"(e2), "v"(e3));
      uint2 wv; wv.x = lo; wv.y = hi;
      int slot = m * 2 + (g >> 1);
      *(uint2*)((char*)PldsW + lrow * 128 + ((slot ^ (lrow & 7)) << 4) + (g & 1) * 8) = wv;
    }
    asm volatile("s_waitcnt lgkmcnt(0)" ::: "memory");   // own Plds writes visible (wave-private)
    __builtin_amdgcn_sched_barrier(0);
    // ---- PV (wave-local): persist-16 x z-64, contract wave's inner-64
    __builtin_amdgcn_s_setprio(1);
    #pragma unroll
    for (int k2p = 0; k2p < 2; k2p++) {
      bf16x8 pa = ld8(PldsW, lrow, k2p * 4 + g);
      #pragma unroll
      for (int n4 = 0; n4 < 4; n4++) {
        bf16x8 pb = ld16(curX, n4 * 16 + lrow, wr * 8 + k2p * 4 + g);
        acc_pv[n4] = __builtin_amdgcn_mfma_f32_16x16x32_bf16(pa, pb, acc_pv[n4], 0, 0, 0);
      }
    }
    __builtin_amdgcn_s_setprio(0);
    wait_vm_lgkm0<0>();
    __builtin_amdgcn_s_barrier();
  }

  // ---- epilogue: Red[wr][p][z] overlay (Ain region retired)
  #pragma unroll
  for (int n4 = 0; n4 < 4; n4++)
    #pragma unroll
    for (int j = 0; j < 4; j++)
      Red[(size_t)(wr * 64 + wcq * 16 + 4 * g + j) * 64 + n4 * 16 + lrow] = acc_pv[n4][j];
  if (DIV && tid < 64) L_lds[tid] = 0.f;
  __syncthreads();
  if (DIV) {
    lsum += __shfl_xor(lsum, 16); lsum += __shfl_xor(lsum, 32);
    if (lane < 16) atomicAdd(&L_lds[wcq * 16 + lane], lsum);
    __syncthreads();
    if (tid < 64) Lg[(size_t)h * NT + p0 + tid] = L_lds[tid];
  }
  // output: thread -> persist row p = tid>>3, z-range (tid&7)*8
  int p = tid >> 3, zb = (tid & 7) * 8;
  float inv = DIV ? 1.0f / L_lds[p] : 1.0f;
  int cbase = DIV ? h64 : TD + h64;
  unsigned short ob[8];
  #pragma unroll
  for (int zz = 0; zz < 8; zz += 4) {
    f32x4 s0 = *(f32x4*)&Red[(size_t)(0 * 64 + p) * 64 + zb + zz];
    f32x4 s1 = *(f32x4*)&Red[(size_t)(1 * 64 + p) * 64 + zb + zz];
    #pragma unroll
    for (int j = 0; j < 4; j++) ob[zz + j] = f2bf((s0[j] + s1[j]) * inv);
  }
  unsigned short* dst = C + (size_t)(p0 + p) * 2048 + cbase + zb;
  *(ushort4*)dst = *(ushort4*)&ob[0];
  *(ushort4*)(dst + 4) = *(ushort4*)&ob[4];
}

// ------------------------------------------------------------------
extern "C" void kernel_launch(void* const* d_in, const int* in_sizes, int n_in,
                              void* d_out, int out_size, void* d_ws, size_t ws_size,
                              hipStream_t stream)
{
  (void)in_sizes; (void)n_in; (void)out_size; (void)ws_size;
  const float* g  = (const float*)d_in[0];
  const float* Wk = (const float*)d_in[1];
  const float* Wq = (const float*)d_in[2];

  char* ws = (char*)d_ws;
  size_t off = 0;
  auto alloc = [&](size_t b) -> char* {
    char* p = ws + off; off += (b + 255) & ~((size_t)255); return p;
  };
  unsigned short* gbf  = (unsigned short*)alloc((size_t)NT * TD * 2);     // 4 MB
  unsigned short* wkq  = (unsigned short*)alloc((size_t)2 * TD * TD * 2); // 4 MB
  unsigned short* twqk = (unsigned short*)alloc((size_t)TD * 2048 * 2);   // 4 MB
  unsigned short* CKQ  = (unsigned short*)alloc((size_t)NT * 2048 * 2);   // 8 MB
  unsigned short* TKQ  = (unsigned short*)alloc((size_t)NT * 2048 * 2);   // 8 MB
  unsigned short* CB12 = (unsigned short*)alloc((size_t)NT * 2048 * 2);   // 8 MB
  unsigned short* QsT  = (unsigned short*)alloc((size_t)TD * NT * 2);     // 4 MB
  float*          Lbuf = (float*)alloc((size_t)NH * NT * 4);              // 128 KB

  prep_kernel<<<dim3(4096), dim3(256), 0, stream>>>(g, Wk, Wq, gbf, wkq, twqk);

  // K,Q = g * [Wk;Wq]^T -> CKQ [tok][2048] (K cols scaled by SCL), TKQ = CKQ^T unscaled
  btg2_kernel<128, 64, 0, 2><<<dim3(16, 32), dim3(256), 0, stream>>>(
      gbf, TD, wkq, TD, TD, (void*)CKQ, (void*)TKQ);

  // F1: B1 (normalized) -> CB12 cols [h*64, h*64+64), plus L
  fused_kernel<true><<<dim3(32, NH), dim3(512), 0, stream>>>(CKQ, TKQ, CB12, Lbuf);

  // Qn^T = Q^T / L
  qst_kernel<<<dim3(1024), dim3(256), 0, stream>>>(TKQ, Lbuf, QsT);

  // F2: B2 -> CB12 cols [1024+h*64, ...)
  fused_kernel<false><<<dim3(32, NH), dim3(512), 0, stream>>>(CKQ, QsT, CB12, nullptr);

  // out = -( CB12 * twqk^T )   (f32)
  btg2_kernel<64, 64, 4, 3><<<dim3(32, 16), dim3(256), 0, stream>>>(
      CB12, 2048, twqk, 2048, 2048, d_out, nullptr);
}